// Round 21
// baseline (177.657 us; speedup 1.0000x reference)
//
#include <hip/hip_runtime.h>

#define N_IMG 4
#define E_DIM 16
#define G_PIX 80000               // float4 groups per image-channel (320000/4)
#define C_CLS 20
#define CK 19                     // classes 1..19 (IGNORE = 0)
#define NREP 8                    // LDS replica count for atomic binning
#define SL1 128                   // k_sums pixel slices per image
#define R1 (G_PIX / SL1)          // 625 groups per k_sums block (exact)
#define GRID1 (SL1 * N_IMG)       // 512 blocks = 2 per CU (ample for BW-bound)
#define SL2 256                   // k_var slices per image
#define R2 ((G_PIX + SL2 - 1) / SL2) // 313 (tail-checked)
#define GRID2 (SL2 * N_IMG)       // 1024 blocks
#define MSTRIDE 17                // lmean stride: 20 labels -> 20 distinct banks
#define LS_SLOT 17                // u64 slots per (class, replica): 16 channels + pad
#define SCALE_F 16777216.0f       // 2^24 fixed-point scale
#define INV_SCALE (1.0f / 16777216.0f)

// ws layout (BYTES). All-integer accumulators: global FLOAT atomicAdd compiles to a
// CAS retry loop without -munsafe-fp-atomics (measured r10: k_var flat 55us whether
// FETCH=44MB or 65KB -> serialized epilogue). Integer atomics are native (r19: -36us).
#define SUMS_OFF 0                                  // i64[4][20][16]   10240 B
#define CNT_OFF  (N_IMG * C_CLS * E_DIM * 8)        // u32[4][20]       320 B
#define PART_OFF (CNT_OFF + N_IMG * C_CLS * 4)      // float[1024]      4096 B
#define DONE_OFF (PART_OFF + GRID2 * 4)             // u32 done counter
#define WS_BYTES (DONE_OFF + 4)

static_assert(G_PIX % SL1 == 0, "k_sums slicing must be exact");

// ---------------- Kernel 1: per-class sums + counts via native integer atomics ----------
// NOTE (measured r2): float LDS atomicAdd = CAS loop on gfx950 (310us vs 65us).
// NOTE (measured r8): never cap MLP — keep independent loads issued before use.
// NOTE (measured r10/r19): float GLOBAL atomicAdd is also a CAS loop -> u64/u32 only.
// EG=16: target read ONCE (was 2x), no divergent count path, deeper per-iter MLP.
__global__ __launch_bounds__(256, 4) void k_sums(const float* __restrict__ emb,
                                                 const int* __restrict__ target,
                                                 char* __restrict__ wsb) {
    __shared__ unsigned long long ls[C_CLS][NREP][LS_SLOT];   // 21760 B
    __shared__ unsigned int lc[C_CLS][NREP];                  // 640 B

    const int tid = threadIdx.x;
    const int b = blockIdx.x;
    const int n = b & 3;
    const int slice = b >> 2;                  // 0..SL1-1

    unsigned long long* lsf = &ls[0][0][0];
    for (int i = tid; i < C_CLS * NREP * LS_SLOT; i += 256) lsf[i] = 0ull;
    for (int i = tid; i < C_CLS * NREP; i += 256) (&lc[0][0])[i] = 0u;
    __syncthreads();

    const float4* emb0 = (const float4*)emb + (size_t)n * E_DIM * G_PIX;
    const int4* tgt4 = (const int4*)target + (size_t)n * G_PIX;
    const int r = tid & (NREP - 1);

#define QADD(p, idx, val) \
    atomicAdd((p) + (idx), (unsigned long long)(long long)__float2int_rn((val) * SCALE_F))

    const int g1 = (slice + 1) * R1;
    for (int g = slice * R1 + tid; g < g1; g += 256) {
        const int4 lb = tgt4[g];
        // all 17 loads independent -> issued before first use (MLP)
        float4 v[E_DIM];
#pragma unroll
        for (int k = 0; k < E_DIM; k++) v[k] = emb0[(size_t)k * G_PIX + g];

        unsigned long long* px = &ls[lb.x][r][0];
        unsigned long long* py = &ls[lb.y][r][0];
        unsigned long long* pz = &ls[lb.z][r][0];
        unsigned long long* pw = &ls[lb.w][r][0];
#pragma unroll
        for (int k = 0; k < E_DIM; k++) {
            QADD(px, k, v[k].x);
            QADD(py, k, v[k].y);
            QADD(pz, k, v[k].z);
            QADD(pw, k, v[k].w);
        }
        atomicAdd(&lc[lb.x][r], 1u); atomicAdd(&lc[lb.y][r], 1u);
        atomicAdd(&lc[lb.z][r], 1u); atomicAdd(&lc[lb.w][r], 1u);
    }
#undef QADD
    __syncthreads();

    // flush: combine replicas, native u64 atomic to global (fire-and-forget, no CAS)
    unsigned long long* gsum = (unsigned long long*)(wsb + SUMS_OFF);
    unsigned int* gcnt = (unsigned int*)(wsb + CNT_OFF);
    for (int i = tid; i < C_CLS * E_DIM; i += 256) {
        const int c = i >> 4, e = i & 15;
        unsigned long long q = 0ull;
#pragma unroll
        for (int rr = 0; rr < NREP; rr++) q += ls[c][rr][e];
        atomicAdd(&gsum[(n * C_CLS + c) * E_DIM + e], q);
    }
    for (int c = tid; c < C_CLS; c += 256) {
        unsigned int s = 0;
#pragma unroll
        for (int rr = 0; rr < NREP; rr++) s += lc[c][rr];
        atomicAdd(&gcnt[n * C_CLS + c], s);
    }
}

// -------- Kernel 2: means + distance/reg terms (blocks 0..3) + variance term + finalize ----
// Epilogue: plain store to own part[b] slot; native u32 done-counter; LAST arriving
// block reduces the 1024 partials cooperatively and writes out[0] (r8/r19-proven pattern).
__global__ __launch_bounds__(256, 4) void k_var(const float* __restrict__ emb,
                                                const int* __restrict__ target,
                                                char* __restrict__ wsb,
                                                float* __restrict__ out) {
    __shared__ float lmean[C_CLS * MSTRIDE];
    __shared__ float lw[C_CLS];
    __shared__ float red[256];
    __shared__ int last;

    const int tid = threadIdx.x;
    const int b = blockIdx.x;
    const int n = b & 3;
    const int s2 = b >> 2;                     // 0..SL2-1

    const long long* gsum = (const long long*)(wsb + SUMS_OFF);
    const unsigned int* gcnt = (const unsigned int*)(wsb + CNT_OFF);

    for (int i = tid; i < C_CLS * E_DIM; i += 256) {
        const int c = i >> 4, e = i & 15;
        const float cnt = (float)gcnt[n * C_CLS + c];
        const float s = (float)gsum[n * C_CLS * E_DIM + i] * INV_SCALE;
        lmean[c * MSTRIDE + e] = (cnt > 0.f) ? s / cnt : 0.f;
    }
    if (tid < C_CLS) {
        const float cnt = (float)gcnt[n * C_CLS + tid];
        // lw[0] = 0 masks IGNORE pixels branchlessly
        lw[tid] = (tid != 0 && cnt > 0.f) ? 1.0f / (cnt * (float)CK) : 0.f;
    }
    __syncthreads();

    float acc = 0.f;
    if (b < N_IMG) {
        // one block per image computes push + regularizer terms
        for (int idx = tid; idx < CK * CK; idx += 256) {
            const int i = idx / CK + 1, j = idx % CK + 1;
            if (i != j) {
                float sq = 0.f;
#pragma unroll
                for (int e = 0; e < E_DIM; e++) {
                    const float d = lmean[i * MSTRIDE + e] - lmean[j * MSTRIDE + e];
                    sq += d * d;
                }
                const float dm = sqrtf(sq);
                const float h = fmaxf(3.0f - dm, 0.f);   // 2*DELTA_DIST = 3
                acc += h * h;
            }
        }
        acc *= 1.0f / (float)(CK * (CK - 1));            // BETA = 1
        float racc = 0.f;
        for (int c = tid + 1; c < C_CLS; c += 256) {
            float sq = 0.f;
#pragma unroll
            for (int e = 0; e < E_DIM; e++) {
                const float m = lmean[c * MSTRIDE + e];
                sq += m * m;
            }
            racc += sqrtf(sq);
        }
        acc += 0.001f * racc / (float)CK;                // GAMMA = 0.001
    }

    const float4* emb4 = (const float4*)emb + (size_t)n * E_DIM * G_PIX;
    const int4* tgt4 = (const int4*)target + (size_t)n * G_PIX;
    const int gend0 = (s2 + 1) * R2;
    const int gend = (gend0 < G_PIX) ? gend0 : G_PIX;
    for (int g = s2 * R2 + tid; g < gend; g += 256) {
        const int4 lb = tgt4[g];
        // all 16 channel loads issued before use (forced MLP — the r8 lesson)
        float4 v[E_DIM];
#pragma unroll
        for (int e = 0; e < E_DIM; e++) v[e] = emb4[(size_t)e * G_PIX + g];

        const int bx = lb.x * MSTRIDE, by = lb.y * MSTRIDE;
        const int bz = lb.z * MSTRIDE, bw = lb.w * MSTRIDE;
        float sx = 0.f, sy = 0.f, sz = 0.f, sw = 0.f;
#pragma unroll
        for (int e = 0; e < E_DIM; e++) {
            float d;
            d = v[e].x - lmean[bx + e]; sx += d * d;
            d = v[e].y - lmean[by + e]; sy += d * d;
            d = v[e].z - lmean[bz + e]; sz += d * d;
            d = v[e].w - lmean[bw + e]; sw += d * d;
        }
        float h;
        h = fmaxf(sqrtf(sx) - 0.5f, 0.f); acc += h * h * lw[lb.x];
        h = fmaxf(sqrtf(sy) - 0.5f, 0.f); acc += h * h * lw[lb.y];
        h = fmaxf(sqrtf(sz) - 0.5f, 0.f); acc += h * h * lw[lb.z];
        h = fmaxf(sqrtf(sw) - 0.5f, 0.f); acc += h * h * lw[lb.w];
    }

    red[tid] = acc;
    __syncthreads();
    for (int s = 128; s > 0; s >>= 1) {
        if (tid < s) red[tid] += red[tid + s];
        __syncthreads();
    }

    float* part = (float*)(wsb + PART_OFF);
    unsigned* done = (unsigned*)(wsb + DONE_OFF);
    if (tid == 0) {
        part[b] = red[0];                      // plain store, own slot
        __threadfence();                       // flush before release
        const unsigned arr = __hip_atomic_fetch_add(done, 1u, __ATOMIC_ACQ_REL,
                                                    __HIP_MEMORY_SCOPE_AGENT);
        last = (arr == GRID2 - 1) ? 1 : 0;
    }
    __syncthreads();

    if (last) {
        // last block: all part[] stores ordered-before our acquiring fetch_add
        float a = 0.f;
        for (int i = tid; i < GRID2; i += 256)
            a += __hip_atomic_load(&part[i], __ATOMIC_RELAXED, __HIP_MEMORY_SCOPE_AGENT);
        red[tid] = a;
        __syncthreads();
        for (int s = 128; s > 0; s >>= 1) {
            if (tid < s) red[tid] += red[tid + s];
            __syncthreads();
        }
        if (tid == 0) out[0] = red[0] * 0.25f; // mean over 4 images
    }
}

extern "C" void kernel_launch(void* const* d_in, const int* in_sizes, int n_in,
                              void* d_out, int out_size, void* d_ws, size_t ws_size,
                              hipStream_t stream) {
    const float* emb = (const float*)d_in[0];
    const int* target = (const int*)d_in[1];
    float* out = (float*)d_out;
    char* wsb = (char*)d_ws;

    hipMemsetAsync(d_ws, 0, WS_BYTES, stream);
    k_sums<<<dim3(GRID1), 256, 0, stream>>>(emb, target, wsb);
    k_var<<<dim3(GRID2), 256, 0, stream>>>(emb, target, wsb, out);
}